// Round 7
// baseline (534.583 us; speedup 1.0000x reference)
//
#include <hip/hip_runtime.h>
#include <math.h>

#define BLK 256
// bucketed CSR build: 512 dst-nodes per bucket
#define BKT_BITS 9
#define BKT (1<<BKT_BITS)
#define MAXNB 256
#define EB 8192   // edges per bin-block

typedef __attribute__((ext_vector_type(8))) short bf16x8;
typedef __attribute__((ext_vector_type(4))) float f32x4;

__device__ inline unsigned short f2b(float f){
  union { float f; unsigned int u; } v; v.f = f;
  unsigned int u = v.u;
  return (unsigned short)((u + 0x7FFF + ((u >> 16) & 1)) >> 16);
}
__device__ inline float b2f_lo(unsigned int u){
  union { unsigned int u; float f; } v; v.u = u << 16; return v.f;
}
__device__ inline float b2f_hi(unsigned int u){
  union { unsigned int u; float f; } v; v.u = u & 0xFFFF0000u; return v.f;
}

// ---------------- bucketed CSR build ----------------

__global__ __launch_bounds__(256)
void bhistA(const int* __restrict__ dst, int* __restrict__ bhist, int E, int NB){
  __shared__ int h[MAXNB];
  int t = threadIdx.x;
  for (int i=t;i<NB;i+=256) h[i]=0;
  __syncthreads();
  int base = blockIdx.x*EB;
  #pragma unroll
  for (int k=0;k<EB/256;k++){
    int idx = base + k*256 + t;
    if (idx < E) atomicAdd(&h[dst[idx]>>BKT_BITS], 1);
  }
  __syncthreads();
  for (int i=t;i<NB;i+=256) if (h[i]) atomicAdd(&bhist[i], h[i]);
}

__global__ void bscanB(const int* __restrict__ bhist, int* __restrict__ boffs,
                       int* __restrict__ bcur, int NB){
  __shared__ int h[MAXNB];
  int t = threadIdx.x;
  int v0 = (t < NB) ? bhist[t] : 0;
  h[t] = v0; __syncthreads();
  for (int off=1; off<MAXNB; off<<=1){
    int v = (t>=off)?h[t-off]:0;
    __syncthreads();
    h[t]+=v;
    __syncthreads();
  }
  if (t<NB){ int excl=h[t]-v0; boffs[t]=excl; bcur[t]=excl; }
}

// bin edges into buckets via LDS sort; packed 4B output (src<<9 | dst&511)
__global__ __launch_bounds__(256)
void binC(const int* __restrict__ src, const int* __restrict__ dst, int* __restrict__ bcur,
          unsigned int* __restrict__ bins, int E, int NB){
  __shared__ int lh[MAXNB];
  __shared__ int lofs[MAXNB];
  __shared__ int lcur[MAXNB];
  __shared__ int gres[MAXNB];
  __shared__ __attribute__((aligned(16))) int2 buf[EB];
  int t = threadIdx.x;
  for (int i=t;i<NB;i+=256) lh[i]=0;
  __syncthreads();
  int base = blockIdx.x*EB;
  #pragma unroll
  for (int k=0;k<EB/256;k++){
    int idx = base + k*256 + t;
    if (idx < E) atomicAdd(&lh[dst[idx]>>BKT_BITS], 1);
  }
  __syncthreads();
  if (t==0){ int run=0; for (int b=0;b<NB;b++){ lofs[b]=run; run+=lh[b]; } }
  __syncthreads();
  if (t<NB){
    lcur[t] = lofs[t];
    gres[t] = lh[t] ? atomicAdd(&bcur[t], lh[t]) : 0;
  }
  __syncthreads();
  #pragma unroll
  for (int k=0;k<EB/256;k++){
    int idx = base + k*256 + t;
    if (idx < E){
      int d = dst[idx];
      int p = atomicAdd(&lcur[d>>BKT_BITS], 1);
      buf[p] = make_int2(src[idx], d);
    }
  }
  __syncthreads();
  int total = E - base; if (total > EB) total = EB;
  for (int i=t; i<total; i+=256){
    int2 pr = buf[i];
    int b = pr.y>>BKT_BITS;
    bins[gres[b] + (i - lofs[b])] = ((unsigned)pr.x << BKT_BITS) | (unsigned)(pr.y & (BKT-1));
  }
}

// per-node degree from packed bins
__global__ __launch_bounds__(256)
void bdegD(const unsigned int* __restrict__ bins, const int* __restrict__ boffs,
           const int* __restrict__ bhist, int* __restrict__ deg, int N){
  __shared__ int dcnt[BKT];
  int b = blockIdx.x;
  for (int i=threadIdx.x;i<BKT;i+=256) dcnt[i]=0;
  __syncthreads();
  int s = boffs[b], cnt = bhist[b];
  for (int i=threadIdx.x;i<cnt;i+=256)
    atomicAdd(&dcnt[bins[s+i] & (BKT-1)], 1);
  __syncthreads();
  int base = b<<BKT_BITS;
  for (int i=threadIdx.x;i<BKT;i+=256){
    int node = base+i;
    if (node < N) deg[node] = dcnt[i];
  }
}

// fused: chained scan (deg -> rowptr) + dinv + W1 transpose/cvt (extra blocks)
// SB scan blocks (1024 items each) + 128 wcvt blocks; all <= 256 CUs -> co-resident
__global__ __launch_bounds__(256)
void scan_fused(const int* __restrict__ deg, int* __restrict__ rowptr,
                float* __restrict__ dinv, int* __restrict__ gflag,
                const float* __restrict__ W1, unsigned short* __restrict__ W1T,
                int N, int SB){
  int b = blockIdx.x;
  if (b >= SB){
    int t = (b - SB)*256 + threadIdx.x;
    if (t < 256*128){
      int k = t >> 7, n = t & 127;
      W1T[n*256 + k] = f2b(W1[t]);
    }
    return;
  }
  __shared__ int sd[256];
  __shared__ int sbase;
  int tid = threadIdx.x;
  int base_i = b * 1024;
  int vals[4]; int tsum = 0;
  #pragma unroll
  for (int q=0;q<4;q++){
    int idx = base_i + tid*4 + q;
    int v = 0;
    if (idx < N){
      int dg = deg[idx];
      v = dg + 1;                       // +1 self-loop
      dinv[idx] = rsqrtf((float)(dg + 1));
    }
    vals[q] = v; tsum += v;
  }
  sd[tid] = tsum; __syncthreads();
  for (int off=1; off<256; off<<=1){
    int v = (tid >= off) ? sd[tid-off] : 0;
    __syncthreads();
    sd[tid] += v;
    __syncthreads();
  }
  int total = sd[255];
  if (tid == 0){
    int basev = 0;
    if (b > 0){
      int f;
      do {
        f = __hip_atomic_load(&gflag[b-1], __ATOMIC_ACQUIRE, __HIP_MEMORY_SCOPE_AGENT);
      } while (f == 0);
      basev = f - 1;
    }
    __hip_atomic_store(&gflag[b], basev + total + 1, __ATOMIC_RELEASE, __HIP_MEMORY_SCOPE_AGENT);
    sbase = basev;
    if (b == 0) rowptr[0] = 0;
  }
  __syncthreads();
  int gbase = sbase;
  int run = sd[tid] - tsum;
  #pragma unroll
  for (int q=0;q<4;q++){
    run += vals[q];
    int idx = base_i + tid*4 + q;
    if (idx < N) rowptr[idx+1] = gbase + run;
  }
}

// per-bucket CSR fill — LDS cursors, single-CU full-line col writes
__global__ __launch_bounds__(256)
void bfillF(const unsigned int* __restrict__ bins, const int* __restrict__ boffs,
            const int* __restrict__ bhist, const int* __restrict__ rowptr,
            int* __restrict__ col, int N){
  __shared__ int rp[BKT];
  __shared__ int cur[BKT];
  int b = blockIdx.x;
  int base = b<<BKT_BITS;
  for (int i=threadIdx.x;i<BKT;i+=256){
    int node = base+i;
    rp[i] = (node < N) ? rowptr[node] : 0;
    cur[i] = 0;
  }
  __syncthreads();
  int s = boffs[b], cnt = bhist[b];
  for (int i=threadIdx.x;i<cnt;i+=256){
    unsigned pk = bins[s+i];
    int ln = pk & (BKT-1);
    int slot = atomicAdd(&cur[ln], 1);
    col[rp[ln] + slot] = (int)(pk >> BKT_BITS);
  }
  __syncthreads();
  for (int i=threadIdx.x;i<BKT;i+=256){
    int node = base+i;
    if (node < N) col[rp[i] + cur[i]] = node;   // self-loop last
  }
}

// ---------------- GEMM1 (MFMA bf16): h1b[r] = dinv[r] * (x @ W1)[r], bf16 ----------------

#define XPAD 40

__global__ __launch_bounds__(256)
void gemm1_mfma(const float* __restrict__ X, const unsigned short* __restrict__ W1T,
                const float* __restrict__ dinv, unsigned short* __restrict__ H1B, int M){
  __shared__ __attribute__((aligned(16))) unsigned short xs[128*XPAD];
  __shared__ __attribute__((aligned(16))) unsigned short wt[128*XPAD];
  const int tid = threadIdx.x;
  const int wave = tid >> 6, lane = tid & 63;
  const int quad = lane >> 4, l16 = lane & 15;
  const int row0 = blockIdx.x * 128;

  f32x4 acc[2][8];
  #pragma unroll
  for (int i=0;i<2;i++)
    #pragma unroll
    for (int j=0;j<8;j++) acc[i][j] = (f32x4){0.f,0.f,0.f,0.f};

  const int r    = tid >> 1;
  const int half = tid & 1;

  for (int k0 = 0; k0 < 256; k0 += 32){
    {
      int gr = row0 + r;
      const float* xp = X + (size_t)gr*256 + k0 + half*16;
      unsigned short* xd = xs + r*XPAD + half*16;
      #pragma unroll
      for (int q=0;q<4;q++){
        float4 v = (gr < M) ? *(const float4*)(xp + q*4) : make_float4(0.f,0.f,0.f,0.f);
        ushort4 b;
        b.x = f2b(v.x); b.y = f2b(v.y); b.z = f2b(v.z); b.w = f2b(v.w);
        *(ushort4*)(xd + q*4) = b;
      }
    }
    {
      const unsigned short* wp = W1T + r*256 + k0 + half*16;
      unsigned short* wd = wt + r*XPAD + half*16;
      uint4 a = *(const uint4*)wp;
      uint4 c = *(const uint4*)(wp + 8);
      *(uint4*)wd = a;
      *(uint4*)(wd + 8) = c;
    }
    __syncthreads();

    bf16x8 bfr[8];
    #pragma unroll
    for (int ct=0; ct<8; ct++)
      bfr[ct] = *(bf16x8*)(wt + (ct*16 + l16)*XPAD + quad*8);
    #pragma unroll
    for (int rt=0; rt<2; rt++){
      bf16x8 a = *(bf16x8*)(xs + (wave*32 + rt*16 + l16)*XPAD + quad*8);
      #pragma unroll
      for (int ct=0; ct<8; ct++)
        acc[rt][ct] = __builtin_amdgcn_mfma_f32_16x16x32_bf16(a, bfr[ct], acc[rt][ct], 0, 0, 0);
    }
    __syncthreads();
  }

  #pragma unroll
  for (int rt=0; rt<2; rt++){
    int rbase = row0 + wave*32 + rt*16 + quad*4;
    #pragma unroll
    for (int rg=0; rg<4; rg++){
      int grow = rbase + rg;
      if (grow < M){
        float dv = dinv[grow];
        #pragma unroll
        for (int ct=0; ct<8; ct++)
          H1B[(size_t)grow*128 + ct*16 + l16] = f2b(dv * acc[rt][ct][rg]);
      }
    }
  }
}

// ---------------- agg1: wave/node gather (4-wide) + dinv + bias + ReLU -> bf16 r1 ----------------

__global__ __launch_bounds__(256)
void agg1_kernel(const unsigned short* __restrict__ H1B, const int* __restrict__ rowptr,
                 const int* __restrict__ col, const float* __restrict__ dinv,
                 const float* __restrict__ b1, unsigned int* __restrict__ R1B, int N){
  int node = blockIdx.x * 4 + (threadIdx.x >> 6);
  int lane = threadIdx.x & 63;
  if (node >= N) return;
  int s = rowptr[node], e = rowptr[node+1];
  float a0=0.f,a1=0.f,b0=0.f,b1v=0.f,c0=0.f,c1=0.f,d0=0.f,d1=0.f;
  int j = s;
  for (; j+3 < e; j += 4){
    int cA = col[j], cB = col[j+1], cC = col[j+2], cD = col[j+3];
    unsigned uA = *(const unsigned*)(H1B + (size_t)cA*128 + lane*2);
    unsigned uB = *(const unsigned*)(H1B + (size_t)cB*128 + lane*2);
    unsigned uC = *(const unsigned*)(H1B + (size_t)cC*128 + lane*2);
    unsigned uD = *(const unsigned*)(H1B + (size_t)cD*128 + lane*2);
    a0 += b2f_lo(uA); a1 += b2f_hi(uA);
    b0 += b2f_lo(uB); b1v+= b2f_hi(uB);
    c0 += b2f_lo(uC); c1 += b2f_hi(uC);
    d0 += b2f_lo(uD); d1 += b2f_hi(uD);
  }
  for (; j < e; j++){
    int cA = col[j];
    unsigned uA = *(const unsigned*)(H1B + (size_t)cA*128 + lane*2);
    a0 += b2f_lo(uA); a1 += b2f_hi(uA);
  }
  float dv = dinv[node];
  float acc0 = (a0+b0)+(c0+d0);
  float acc1 = (a1+b1v)+(c1+d1);
  float r0 = fmaxf(dv*acc0 + b1[lane*2],     0.f);
  float r1 = fmaxf(dv*acc1 + b1[lane*2 + 1], 0.f);
  R1B[(size_t)node*64 + lane] = (unsigned)f2b(r0) | ((unsigned)f2b(r1) << 16);
}

// ---------------- GEMM2: h2b[r] = bf16( dinv[r] * (r1[r] @ W2) ), packed 32B stride ----------------

__global__ __launch_bounds__(256)
void gemm2_kernel(const unsigned int* __restrict__ R1B, const float* __restrict__ W2,
                  const float* __restrict__ dinv, unsigned int* __restrict__ H2B, int M){
  __shared__ float w2s[128*10];
  for (int i = threadIdx.x; i < 128*10; i += blockDim.x) w2s[i] = W2[i];
  __syncthreads();
  int r = blockIdx.x*blockDim.x + threadIdx.x;
  if (r >= M) return;
  float acc[10];
  #pragma unroll
  for (int c=0;c<10;c++) acc[c] = 0.f;
  const unsigned int* row = R1B + (size_t)r*64;
  for (int k=0;k<64;k+=4){
    uint4 u = *(const uint4*)(row + k);
    float f0 = b2f_lo(u.x), f1 = b2f_hi(u.x);
    float f2 = b2f_lo(u.y), f3 = b2f_hi(u.y);
    float f4 = b2f_lo(u.z), f5 = b2f_hi(u.z);
    float f6 = b2f_lo(u.w), f7 = b2f_hi(u.w);
    #pragma unroll
    for (int c=0;c<10;c++){
      acc[c] += f0*w2s[(2*k+0)*10+c] + f1*w2s[(2*k+1)*10+c]
              + f2*w2s[(2*k+2)*10+c] + f3*w2s[(2*k+3)*10+c]
              + f4*w2s[(2*k+4)*10+c] + f5*w2s[(2*k+5)*10+c]
              + f6*w2s[(2*k+6)*10+c] + f7*w2s[(2*k+7)*10+c];
    }
  }
  float dv = dinv[r];
  unsigned int p[5];
  #pragma unroll
  for (int c=0;c<5;c++)
    p[c] = (unsigned)f2b(dv*acc[2*c]) | ((unsigned)f2b(dv*acc[2*c+1]) << 16);
  unsigned int* op = H2B + (size_t)r*8;
  *(uint4*)op = make_uint4(p[0],p[1],p[2],p[3]);
  op[4] = p[4];
}

// ---------------- agg2 + bias + log_softmax (2-wide, bf16 h2) ----------------

__global__ __launch_bounds__(256)
void agg2_softmax_kernel(const unsigned int* __restrict__ H2B, const int* __restrict__ rowptr,
                         const int* __restrict__ col, const float* __restrict__ dinv,
                         const float* __restrict__ b2, float* __restrict__ out, int N){
  int i = blockIdx.x*blockDim.x + threadIdx.x;
  if (i >= N) return;
  float acc[10], acc2[10];
  #pragma unroll
  for (int c=0;c<10;c++){ acc[c] = 0.f; acc2[c] = 0.f; }
  int s = rowptr[i], e = rowptr[i+1];
  int j = s;
  for (; j+1 < e; j += 2){
    const unsigned int* hA = H2B + (size_t)col[j]*8;
    const unsigned int* hB = H2B + (size_t)col[j+1]*8;
    uint4 a = *(const uint4*)hA; unsigned a4 = hA[4];
    uint4 b = *(const uint4*)hB; unsigned b4 = hB[4];
    acc[0]+=b2f_lo(a.x); acc[1]+=b2f_hi(a.x); acc[2]+=b2f_lo(a.y); acc[3]+=b2f_hi(a.y);
    acc[4]+=b2f_lo(a.z); acc[5]+=b2f_hi(a.z); acc[6]+=b2f_lo(a.w); acc[7]+=b2f_hi(a.w);
    acc[8]+=b2f_lo(a4);  acc[9]+=b2f_hi(a4);
    acc2[0]+=b2f_lo(b.x); acc2[1]+=b2f_hi(b.x); acc2[2]+=b2f_lo(b.y); acc2[3]+=b2f_hi(b.y);
    acc2[4]+=b2f_lo(b.z); acc2[5]+=b2f_hi(b.z); acc2[6]+=b2f_lo(b.w); acc2[7]+=b2f_hi(b.w);
    acc2[8]+=b2f_lo(b4);  acc2[9]+=b2f_hi(b4);
  }
  if (j < e){
    const unsigned int* hA = H2B + (size_t)col[j]*8;
    uint4 a = *(const uint4*)hA; unsigned a4 = hA[4];
    acc[0]+=b2f_lo(a.x); acc[1]+=b2f_hi(a.x); acc[2]+=b2f_lo(a.y); acc[3]+=b2f_hi(a.y);
    acc[4]+=b2f_lo(a.z); acc[5]+=b2f_hi(a.z); acc[6]+=b2f_lo(a.w); acc[7]+=b2f_hi(a.w);
    acc[8]+=b2f_lo(a4);  acc[9]+=b2f_hi(a4);
  }
  float dv = dinv[i];
  #pragma unroll
  for (int f=0;f<10;f++) acc[f] = dv*(acc[f] + acc2[f]) + b2[f];
  float m = acc[0];
  #pragma unroll
  for (int f=1;f<10;f++) m = fmaxf(m, acc[f]);
  float sum = 0.f;
  #pragma unroll
  for (int f=0;f<10;f++) sum += expf(acc[f] - m);
  float lg = m + logf(sum);
  #pragma unroll
  for (int f=0;f<10;f++) out[(size_t)i*10 + f] = acc[f] - lg;
}

// ---------------- launch ----------------

extern "C" void kernel_launch(void* const* d_in, const int* in_sizes, int n_in,
                              void* d_out, int out_size, void* d_ws, size_t ws_size,
                              hipStream_t stream){
  const float* x    = (const float*)d_in[0];
  const int*   ei   = (const int*)d_in[1];
  const float* W1   = (const float*)d_in[2];
  const float* b1   = (const float*)d_in[3];
  const float* W2   = (const float*)d_in[4];
  const float* b2   = (const float*)d_in[5];
  float* out = (float*)d_out;

  const int N = in_sizes[0] / 256;   // 100000
  const int E = in_sizes[1] / 2;     // 1600000
  const int NNZ = E + N;
  const int* src = ei;
  const int* dst = ei + E;
  const int NB = (N + BKT - 1) >> BKT_BITS;          // 196
  const int SB = (N + 1023) / 1024;                  // 98 scan blocks
  const int WB = 128;                                // wcvt blocks

  char* ws = (char*)d_ws;
  size_t off = 0;
  auto alloc = [&](size_t bytes)->char*{
    char* p = ws + off;
    off = (off + bytes + 255) & ~(size_t)255;
    return p;
  };
  int*   zreg   = (int*)  alloc((size_t)(MAXNB + 128)*4);  // bhist + gflag, one memset
  int*   bhist  = zreg;
  int*   gflag  = zreg + MAXNB;
  int*   deg    = (int*)  alloc((size_t)N*4);
  float* dinv   = (float*)alloc((size_t)N*4);
  int*   rowptr = (int*)  alloc((size_t)(N+1)*4);
  int*   boffs  = (int*)  alloc((size_t)MAXNB*4);
  int*   bcur   = (int*)  alloc((size_t)MAXNB*4);
  unsigned int* bins = (unsigned int*)alloc((size_t)E*4);
  int*   col    = (int*)  alloc((size_t)NNZ*4);
  unsigned short* w1t = (unsigned short*)alloc((size_t)128*256*2);
  unsigned short* h1b = (unsigned short*)alloc((size_t)N*128*2);
  unsigned int*   r1b = (unsigned int*)  alloc((size_t)N*64*4);
  unsigned int*   h2b = (unsigned int*)  alloc((size_t)N*8*4);
  (void)ws_size;

  hipMemsetAsync(zreg, 0, (size_t)(MAXNB + 128)*4, stream);

  const int NCB = (E + EB - 1) / EB;

  bhistA<<<NCB, 256, 0, stream>>>(dst, bhist, E, NB);
  bscanB<<<1, MAXNB, 0, stream>>>(bhist, boffs, bcur, NB);
  binC<<<NCB, 256, 0, stream>>>(src, dst, bcur, bins, E, NB);
  bdegD<<<NB, 256, 0, stream>>>(bins, boffs, bhist, deg, N);
  scan_fused<<<SB + WB, 256, 0, stream>>>(deg, rowptr, dinv, gflag, W1, w1t, N, SB);
  bfillF<<<NB, 256, 0, stream>>>(bins, boffs, bhist, rowptr, col, N);

  gemm1_mfma<<<(N+127)/128, 256, 0, stream>>>(x, w1t, dinv, h1b, N);
  agg1_kernel<<<(N+3)/4, 256, 0, stream>>>(h1b, rowptr, col, dinv, b1, r1b, N);
  gemm2_kernel<<<(N+BLK-1)/BLK, BLK, 0, stream>>>(r1b, W2, dinv, h2b, N);
  agg2_softmax_kernel<<<(N+BLK-1)/BLK, BLK, 0, stream>>>(h2b, rowptr, col, dinv, b2, out, N);
}

// Round 8
// 386.083 us; speedup vs baseline: 1.3846x; 1.3846x over previous
//
#include <hip/hip_runtime.h>
#include <math.h>

#define BLK 256
#define SCAN_CHUNK 1024
// bucketed CSR build: 512 dst-nodes per bucket
#define BKT_BITS 9
#define BKT (1<<BKT_BITS)
#define MAXNB 256
#define EB 8192   // edges per bin-block

typedef __attribute__((ext_vector_type(8))) short bf16x8;
typedef __attribute__((ext_vector_type(4))) float f32x4;

__device__ inline unsigned short f2b(float f){
  union { float f; unsigned int u; } v; v.f = f;
  unsigned int u = v.u;
  return (unsigned short)((u + 0x7FFF + ((u >> 16) & 1)) >> 16);
}
__device__ inline float b2f_lo(unsigned int u){
  union { unsigned int u; float f; } v; v.u = u << 16; return v.f;
}
__device__ inline float b2f_hi(unsigned int u){
  union { unsigned int u; float f; } v; v.u = u & 0xFFFF0000u; return v.f;
}

// ---------------- bucketed CSR build ----------------

__global__ __launch_bounds__(256)
void bhistA(const int* __restrict__ dst, int* __restrict__ bhist, int E, int NB){
  __shared__ int h[MAXNB];
  int t = threadIdx.x;
  for (int i=t;i<NB;i+=256) h[i]=0;
  __syncthreads();
  int base = blockIdx.x*EB;
  #pragma unroll
  for (int k=0;k<EB/256;k++){
    int idx = base + k*256 + t;
    if (idx < E) atomicAdd(&h[dst[idx]>>BKT_BITS], 1);
  }
  __syncthreads();
  for (int i=t;i<NB;i+=256) if (h[i]) atomicAdd(&bhist[i], h[i]);
}

__global__ void bscanB(const int* __restrict__ bhist, int* __restrict__ boffs,
                       int* __restrict__ bcur, int NB){
  __shared__ int h[MAXNB];
  int t = threadIdx.x;
  int v0 = (t < NB) ? bhist[t] : 0;
  h[t] = v0; __syncthreads();
  for (int off=1; off<MAXNB; off<<=1){
    int v = (t>=off)?h[t-off]:0;
    __syncthreads();
    h[t]+=v;
    __syncthreads();
  }
  if (t<NB){ int excl=h[t]-v0; boffs[t]=excl; bcur[t]=excl; }
}

// bin edges into buckets via LDS sort; packed 4B output (src<<9 | dst&511)
__global__ __launch_bounds__(256)
void binC(const int* __restrict__ src, const int* __restrict__ dst, int* __restrict__ bcur,
          unsigned int* __restrict__ bins, int E, int NB){
  __shared__ int lh[MAXNB];
  __shared__ int lofs[MAXNB];
  __shared__ int lcur[MAXNB];
  __shared__ int gres[MAXNB];
  __shared__ __attribute__((aligned(16))) int2 buf[EB];
  int t = threadIdx.x;
  for (int i=t;i<NB;i+=256) lh[i]=0;
  __syncthreads();
  int base = blockIdx.x*EB;
  #pragma unroll
  for (int k=0;k<EB/256;k++){
    int idx = base + k*256 + t;
    if (idx < E) atomicAdd(&lh[dst[idx]>>BKT_BITS], 1);
  }
  __syncthreads();
  if (t==0){ int run=0; for (int b=0;b<NB;b++){ lofs[b]=run; run+=lh[b]; } }
  __syncthreads();
  if (t<NB){
    lcur[t] = lofs[t];
    gres[t] = lh[t] ? atomicAdd(&bcur[t], lh[t]) : 0;
  }
  __syncthreads();
  #pragma unroll
  for (int k=0;k<EB/256;k++){
    int idx = base + k*256 + t;
    if (idx < E){
      int d = dst[idx];
      int p = atomicAdd(&lcur[d>>BKT_BITS], 1);
      buf[p] = make_int2(src[idx], d);
    }
  }
  __syncthreads();
  int total = E - base; if (total > EB) total = EB;
  for (int i=t; i<total; i+=256){
    int2 pr = buf[i];
    int b = pr.y>>BKT_BITS;
    bins[gres[b] + (i - lofs[b])] = ((unsigned)pr.x << BKT_BITS) | (unsigned)(pr.y & (BKT-1));
  }
}

// per-node degree from packed bins
__global__ __launch_bounds__(256)
void bdegD(const unsigned int* __restrict__ bins, const int* __restrict__ boffs,
           const int* __restrict__ bhist, int* __restrict__ deg, int N){
  __shared__ int dcnt[BKT];
  int b = blockIdx.x;
  for (int i=threadIdx.x;i<BKT;i+=256) dcnt[i]=0;
  __syncthreads();
  int s = boffs[b], cnt = bhist[b];
  for (int i=threadIdx.x;i<cnt;i+=256)
    atomicAdd(&dcnt[bins[s+i] & (BKT-1)], 1);
  __syncthreads();
  int base = b<<BKT_BITS;
  for (int i=threadIdx.x;i<BKT;i+=256){
    int node = base+i;
    if (node < N) deg[node] = dcnt[i];
  }
}

// scanA (+ dinv fused) + independent wcvt blocks (no inter-block dependency)
__global__ __launch_bounds__(256)
void scanA_fused(const int* __restrict__ deg, int* __restrict__ rowptr,
                 int* __restrict__ bsum, float* __restrict__ dinv,
                 const float* __restrict__ W1, unsigned short* __restrict__ W1T,
                 int N, int SB){
  int b = blockIdx.x;
  if (b >= SB){   // W1 transpose+cvt tail blocks
    int t = (b - SB)*256 + threadIdx.x;
    if (t < 256*128){
      int k = t >> 7, n = t & 127;
      W1T[n*256 + k] = f2b(W1[t]);
    }
    return;
  }
  __shared__ int sd[BLK];
  int tid = threadIdx.x;
  int base = b * SCAN_CHUNK;
  int vals[4]; int tsum = 0;
  #pragma unroll
  for (int q=0;q<4;q++){
    int idx = base + tid*4 + q;
    int v = 0;
    if (idx < N){
      int dg = deg[idx];
      v = dg + 1;                       // +1 self-loop
      dinv[idx] = rsqrtf((float)(dg + 1));
    }
    vals[q] = v; tsum += v;
  }
  sd[tid] = tsum; __syncthreads();
  for (int off=1; off<BLK; off<<=1){
    int v = (tid >= off) ? sd[tid-off] : 0;
    __syncthreads();
    sd[tid] += v;
    __syncthreads();
  }
  int run = sd[tid] - tsum;
  #pragma unroll
  for (int q=0;q<4;q++){
    run += vals[q];
    int idx = base + tid*4 + q;
    if (idx < N) rowptr[idx+1] = run;   // inclusive within chunk
  }
  if (tid == BLK-1) bsum[b] = sd[BLK-1];
}

__global__ void scanB_kernel(int* bsum, int B){
  __shared__ int sd[BLK];
  int tid = threadIdx.x;
  int v0 = (tid < B) ? bsum[tid] : 0;
  sd[tid] = v0; __syncthreads();
  for (int off=1; off<BLK; off<<=1){
    int v = (tid>=off) ? sd[tid-off] : 0;
    __syncthreads();
    sd[tid] += v;
    __syncthreads();
  }
  if (tid < B) bsum[tid] = sd[tid] - v0;   // exclusive block offsets
}

__global__ void scanC_kernel(int* rowptr, const int* __restrict__ bsum, int N){
  int i = blockIdx.x*blockDim.x + threadIdx.x;
  if (i == 0) rowptr[0] = 0;
  if (i < N) rowptr[i+1] += bsum[i / SCAN_CHUNK];
}

// per-bucket CSR fill — LDS cursors, single-CU full-line col writes
__global__ __launch_bounds__(256)
void bfillF(const unsigned int* __restrict__ bins, const int* __restrict__ boffs,
            const int* __restrict__ bhist, const int* __restrict__ rowptr,
            int* __restrict__ col, int N){
  __shared__ int rp[BKT];
  __shared__ int cur[BKT];
  int b = blockIdx.x;
  int base = b<<BKT_BITS;
  for (int i=threadIdx.x;i<BKT;i+=256){
    int node = base+i;
    rp[i] = (node < N) ? rowptr[node] : 0;
    cur[i] = 0;
  }
  __syncthreads();
  int s = boffs[b], cnt = bhist[b];
  for (int i=threadIdx.x;i<cnt;i+=256){
    unsigned pk = bins[s+i];
    int ln = pk & (BKT-1);
    int slot = atomicAdd(&cur[ln], 1);
    col[rp[ln] + slot] = (int)(pk >> BKT_BITS);
  }
  __syncthreads();
  for (int i=threadIdx.x;i<BKT;i+=256){
    int node = base+i;
    if (node < N) col[rp[i] + cur[i]] = node;   // self-loop last
  }
}

// ---------------- GEMM1 (MFMA bf16): h1b[r] = dinv[r] * (x @ W1)[r], bf16 ----------------

#define XPAD 40

__global__ __launch_bounds__(256)
void gemm1_mfma(const float* __restrict__ X, const unsigned short* __restrict__ W1T,
                const float* __restrict__ dinv, unsigned short* __restrict__ H1B, int M){
  __shared__ __attribute__((aligned(16))) unsigned short xs[128*XPAD];
  __shared__ __attribute__((aligned(16))) unsigned short wt[128*XPAD];
  const int tid = threadIdx.x;
  const int wave = tid >> 6, lane = tid & 63;
  const int quad = lane >> 4, l16 = lane & 15;
  const int row0 = blockIdx.x * 128;

  f32x4 acc[2][8];
  #pragma unroll
  for (int i=0;i<2;i++)
    #pragma unroll
    for (int j=0;j<8;j++) acc[i][j] = (f32x4){0.f,0.f,0.f,0.f};

  const int r    = tid >> 1;
  const int half = tid & 1;

  for (int k0 = 0; k0 < 256; k0 += 32){
    {
      int gr = row0 + r;
      const float* xp = X + (size_t)gr*256 + k0 + half*16;
      unsigned short* xd = xs + r*XPAD + half*16;
      #pragma unroll
      for (int q=0;q<4;q++){
        float4 v = (gr < M) ? *(const float4*)(xp + q*4) : make_float4(0.f,0.f,0.f,0.f);
        ushort4 b;
        b.x = f2b(v.x); b.y = f2b(v.y); b.z = f2b(v.z); b.w = f2b(v.w);
        *(ushort4*)(xd + q*4) = b;
      }
    }
    {
      const unsigned short* wp = W1T + r*256 + k0 + half*16;
      unsigned short* wd = wt + r*XPAD + half*16;
      uint4 a = *(const uint4*)wp;
      uint4 c = *(const uint4*)(wp + 8);
      *(uint4*)wd = a;
      *(uint4*)(wd + 8) = c;
    }
    __syncthreads();

    bf16x8 bfr[8];
    #pragma unroll
    for (int ct=0; ct<8; ct++)
      bfr[ct] = *(bf16x8*)(wt + (ct*16 + l16)*XPAD + quad*8);
    #pragma unroll
    for (int rt=0; rt<2; rt++){
      bf16x8 a = *(bf16x8*)(xs + (wave*32 + rt*16 + l16)*XPAD + quad*8);
      #pragma unroll
      for (int ct=0; ct<8; ct++)
        acc[rt][ct] = __builtin_amdgcn_mfma_f32_16x16x32_bf16(a, bfr[ct], acc[rt][ct], 0, 0, 0);
    }
    __syncthreads();
  }

  #pragma unroll
  for (int rt=0; rt<2; rt++){
    int rbase = row0 + wave*32 + rt*16 + quad*4;
    #pragma unroll
    for (int rg=0; rg<4; rg++){
      int grow = rbase + rg;
      if (grow < M){
        float dv = dinv[grow];
        #pragma unroll
        for (int ct=0; ct<8; ct++)
          H1B[(size_t)grow*128 + ct*16 + l16] = f2b(dv * acc[rt][ct][rg]);
      }
    }
  }
}

// ---------------- agg1: wave/node gather (4-wide) + dinv + bias + ReLU -> bf16 r1 ----------------

__global__ __launch_bounds__(256)
void agg1_kernel(const unsigned short* __restrict__ H1B, const int* __restrict__ rowptr,
                 const int* __restrict__ col, const float* __restrict__ dinv,
                 const float* __restrict__ b1, unsigned int* __restrict__ R1B, int N){
  int node = blockIdx.x * 4 + (threadIdx.x >> 6);
  int lane = threadIdx.x & 63;
  if (node >= N) return;
  int s = rowptr[node], e = rowptr[node+1];
  float a0=0.f,a1=0.f,b0=0.f,b1v=0.f,c0=0.f,c1=0.f,d0=0.f,d1=0.f;
  int j = s;
  for (; j+3 < e; j += 4){
    int cA = col[j], cB = col[j+1], cC = col[j+2], cD = col[j+3];
    unsigned uA = *(const unsigned*)(H1B + (size_t)cA*128 + lane*2);
    unsigned uB = *(const unsigned*)(H1B + (size_t)cB*128 + lane*2);
    unsigned uC = *(const unsigned*)(H1B + (size_t)cC*128 + lane*2);
    unsigned uD = *(const unsigned*)(H1B + (size_t)cD*128 + lane*2);
    a0 += b2f_lo(uA); a1 += b2f_hi(uA);
    b0 += b2f_lo(uB); b1v+= b2f_hi(uB);
    c0 += b2f_lo(uC); c1 += b2f_hi(uC);
    d0 += b2f_lo(uD); d1 += b2f_hi(uD);
  }
  for (; j < e; j++){
    int cA = col[j];
    unsigned uA = *(const unsigned*)(H1B + (size_t)cA*128 + lane*2);
    a0 += b2f_lo(uA); a1 += b2f_hi(uA);
  }
  float dv = dinv[node];
  float acc0 = (a0+b0)+(c0+d0);
  float acc1 = (a1+b1v)+(c1+d1);
  float r0 = fmaxf(dv*acc0 + b1[lane*2],     0.f);
  float r1 = fmaxf(dv*acc1 + b1[lane*2 + 1], 0.f);
  R1B[(size_t)node*64 + lane] = (unsigned)f2b(r0) | ((unsigned)f2b(r1) << 16);
}

// ---------------- GEMM2: h2b[r] = bf16( dinv[r] * (r1[r] @ W2) ), packed 32B stride ----------------

__global__ __launch_bounds__(256)
void gemm2_kernel(const unsigned int* __restrict__ R1B, const float* __restrict__ W2,
                  const float* __restrict__ dinv, unsigned int* __restrict__ H2B, int M){
  __shared__ float w2s[128*10];
  for (int i = threadIdx.x; i < 128*10; i += blockDim.x) w2s[i] = W2[i];
  __syncthreads();
  int r = blockIdx.x*blockDim.x + threadIdx.x;
  if (r >= M) return;
  float acc[10];
  #pragma unroll
  for (int c=0;c<10;c++) acc[c] = 0.f;
  const unsigned int* row = R1B + (size_t)r*64;
  for (int k=0;k<64;k+=4){
    uint4 u = *(const uint4*)(row + k);
    float f0 = b2f_lo(u.x), f1 = b2f_hi(u.x);
    float f2 = b2f_lo(u.y), f3 = b2f_hi(u.y);
    float f4 = b2f_lo(u.z), f5 = b2f_hi(u.z);
    float f6 = b2f_lo(u.w), f7 = b2f_hi(u.w);
    #pragma unroll
    for (int c=0;c<10;c++){
      acc[c] += f0*w2s[(2*k+0)*10+c] + f1*w2s[(2*k+1)*10+c]
              + f2*w2s[(2*k+2)*10+c] + f3*w2s[(2*k+3)*10+c]
              + f4*w2s[(2*k+4)*10+c] + f5*w2s[(2*k+5)*10+c]
              + f6*w2s[(2*k+6)*10+c] + f7*w2s[(2*k+7)*10+c];
    }
  }
  float dv = dinv[r];
  unsigned int p[5];
  #pragma unroll
  for (int c=0;c<5;c++)
    p[c] = (unsigned)f2b(dv*acc[2*c]) | ((unsigned)f2b(dv*acc[2*c+1]) << 16);
  unsigned int* op = H2B + (size_t)r*8;
  *(uint4*)op = make_uint4(p[0],p[1],p[2],p[3]);
  op[4] = p[4];
}

// ---------------- agg2 + bias + log_softmax (2-wide, bf16 h2) ----------------

__global__ __launch_bounds__(256)
void agg2_softmax_kernel(const unsigned int* __restrict__ H2B, const int* __restrict__ rowptr,
                         const int* __restrict__ col, const float* __restrict__ dinv,
                         const float* __restrict__ b2, float* __restrict__ out, int N){
  int i = blockIdx.x*blockDim.x + threadIdx.x;
  if (i >= N) return;
  float acc[10], acc2[10];
  #pragma unroll
  for (int c=0;c<10;c++){ acc[c] = 0.f; acc2[c] = 0.f; }
  int s = rowptr[i], e = rowptr[i+1];
  int j = s;
  for (; j+1 < e; j += 2){
    const unsigned int* hA = H2B + (size_t)col[j]*8;
    const unsigned int* hB = H2B + (size_t)col[j+1]*8;
    uint4 a = *(const uint4*)hA; unsigned a4 = hA[4];
    uint4 b = *(const uint4*)hB; unsigned b4 = hB[4];
    acc[0]+=b2f_lo(a.x); acc[1]+=b2f_hi(a.x); acc[2]+=b2f_lo(a.y); acc[3]+=b2f_hi(a.y);
    acc[4]+=b2f_lo(a.z); acc[5]+=b2f_hi(a.z); acc[6]+=b2f_lo(a.w); acc[7]+=b2f_hi(a.w);
    acc[8]+=b2f_lo(a4);  acc[9]+=b2f_hi(a4);
    acc2[0]+=b2f_lo(b.x); acc2[1]+=b2f_hi(b.x); acc2[2]+=b2f_lo(b.y); acc2[3]+=b2f_hi(b.y);
    acc2[4]+=b2f_lo(b.z); acc2[5]+=b2f_hi(b.z); acc2[6]+=b2f_lo(b.w); acc2[7]+=b2f_hi(b.w);
    acc2[8]+=b2f_lo(b4);  acc2[9]+=b2f_hi(b4);
  }
  if (j < e){
    const unsigned int* hA = H2B + (size_t)col[j]*8;
    uint4 a = *(const uint4*)hA; unsigned a4 = hA[4];
    acc[0]+=b2f_lo(a.x); acc[1]+=b2f_hi(a.x); acc[2]+=b2f_lo(a.y); acc[3]+=b2f_hi(a.y);
    acc[4]+=b2f_lo(a.z); acc[5]+=b2f_hi(a.z); acc[6]+=b2f_lo(a.w); acc[7]+=b2f_hi(a.w);
    acc[8]+=b2f_lo(a4);  acc[9]+=b2f_hi(a4);
  }
  float dv = dinv[i];
  #pragma unroll
  for (int f=0;f<10;f++) acc[f] = dv*(acc[f] + acc2[f]) + b2[f];
  float m = acc[0];
  #pragma unroll
  for (int f=1;f<10;f++) m = fmaxf(m, acc[f]);
  float sum = 0.f;
  #pragma unroll
  for (int f=0;f<10;f++) sum += expf(acc[f] - m);
  float lg = m + logf(sum);
  #pragma unroll
  for (int f=0;f<10;f++) out[(size_t)i*10 + f] = acc[f] - lg;
}

// ---------------- launch ----------------

extern "C" void kernel_launch(void* const* d_in, const int* in_sizes, int n_in,
                              void* d_out, int out_size, void* d_ws, size_t ws_size,
                              hipStream_t stream){
  const float* x    = (const float*)d_in[0];
  const int*   ei   = (const int*)d_in[1];
  const float* W1   = (const float*)d_in[2];
  const float* b1   = (const float*)d_in[3];
  const float* W2   = (const float*)d_in[4];
  const float* b2   = (const float*)d_in[5];
  float* out = (float*)d_out;

  const int N = in_sizes[0] / 256;   // 100000
  const int E = in_sizes[1] / 2;     // 1600000
  const int NNZ = E + N;
  const int* src = ei;
  const int* dst = ei + E;
  const int NB = (N + BKT - 1) >> BKT_BITS;          // 196
  const int SB = (N + SCAN_CHUNK - 1) / SCAN_CHUNK;  // 98 scan blocks
  const int WB = 128;                                // wcvt blocks

  char* ws = (char*)d_ws;
  size_t off = 0;
  auto alloc = [&](size_t bytes)->char*{
    char* p = ws + off;
    off = (off + bytes + 255) & ~(size_t)255;
    return p;
  };
  int*   bhist  = (int*)  alloc((size_t)MAXNB*4);
  int*   deg    = (int*)  alloc((size_t)N*4);
  float* dinv   = (float*)alloc((size_t)N*4);
  int*   rowptr = (int*)  alloc((size_t)(N+1)*4);
  int*   bsum   = (int*)  alloc((size_t)BLK*4);
  int*   boffs  = (int*)  alloc((size_t)MAXNB*4);
  int*   bcur   = (int*)  alloc((size_t)MAXNB*4);
  unsigned int* bins = (unsigned int*)alloc((size_t)E*4);
  int*   col    = (int*)  alloc((size_t)NNZ*4);
  unsigned short* w1t = (unsigned short*)alloc((size_t)128*256*2);
  unsigned short* h1b = (unsigned short*)alloc((size_t)N*128*2);
  unsigned int*   r1b = (unsigned int*)  alloc((size_t)N*64*4);
  unsigned int*   h2b = (unsigned int*)  alloc((size_t)N*8*4);
  (void)ws_size;

  hipMemsetAsync(bhist, 0, (size_t)MAXNB*4, stream);

  const int NCB = (E + EB - 1) / EB;

  bhistA<<<NCB, 256, 0, stream>>>(dst, bhist, E, NB);
  bscanB<<<1, MAXNB, 0, stream>>>(bhist, boffs, bcur, NB);
  binC<<<NCB, 256, 0, stream>>>(src, dst, bcur, bins, E, NB);
  bdegD<<<NB, 256, 0, stream>>>(bins, boffs, bhist, deg, N);
  scanA_fused<<<SB + WB, 256, 0, stream>>>(deg, rowptr, bsum, dinv, W1, w1t, N, SB);
  scanB_kernel<<<1, BLK, 0, stream>>>(bsum, SB);
  scanC_kernel<<<(N+BLK-1)/BLK, BLK, 0, stream>>>(rowptr, bsum, N);
  bfillF<<<NB, 256, 0, stream>>>(bins, boffs, bhist, rowptr, col, N);

  gemm1_mfma<<<(N+127)/128, 256, 0, stream>>>(x, w1t, dinv, h1b, N);
  agg1_kernel<<<(N+3)/4, 256, 0, stream>>>(h1b, rowptr, col, dinv, b1, r1b, N);
  gemm2_kernel<<<(N+BLK-1)/BLK, BLK, 0, stream>>>(r1b, W2, dinv, h2b, N);
  agg2_softmax_kernel<<<(N+BLK-1)/BLK, BLK, 0, stream>>>(h2b, rowptr, col, dinv, b2, out, N);
}